// Round 3
// baseline (8037.095 us; speedup 1.0000x reference)
//
#include <hip/hip_runtime.h>
#include <hip/hip_bf16.h>

typedef __bf16 bf16;
typedef __bf16 bf16x8 __attribute__((ext_vector_type(8)));
typedef __bf16 bf16x4 __attribute__((ext_vector_type(4)));
typedef float f32x4 __attribute__((ext_vector_type(4)));

// ---------------------------------------------------------------------------
// Weight conversion fp32 -> bf16, and combined bias bih+bhh
// ---------------------------------------------------------------------------
__global__ void convert_w(const float* __restrict__ Wih, const float* __restrict__ Whh,
                          const float* __restrict__ decW, const float* __restrict__ bih,
                          const float* __restrict__ bhh,
                          bf16* __restrict__ WihB, bf16* __restrict__ WhhB,
                          bf16* __restrict__ decWB, float* __restrict__ bias) {
    int idx = blockIdx.x * 256 + threadIdx.x;
    const int NW = 2 * 2048 * 512;           // 2097152 (both layers)
    if (idx < NW) {
        WihB[idx] = (bf16)Wih[idx];
    } else if (idx < 2 * NW) {
        WhhB[idx - NW] = (bf16)Whh[idx - NW];
    } else if (idx < 2 * NW + 512 * 512) {
        decWB[idx - 2 * NW] = (bf16)decW[idx - 2 * NW];
    } else if (idx < 2 * NW + 512 * 512 + 4096) {
        int j = idx - (2 * NW + 512 * 512);
        bias[j] = bih[j] + bhh[j];
    }
}

// ---------------------------------------------------------------------------
// inp[b,t,h] = emb[trg[b,t], h] + y[b]*yW[h] + yb[h]   (bf16 out)
// ---------------------------------------------------------------------------
__global__ void prep_inp(const int* __restrict__ x, const float* __restrict__ y,
                         const float* __restrict__ emb, const float* __restrict__ yW,
                         const float* __restrict__ yb, bf16* __restrict__ inp) {
    int idx = blockIdx.x * 256 + threadIdx.x;   // total 65536*64
    int bt = idx >> 6;
    int h0 = (idx & 63) * 8;
    int b = bt >> 7, t = bt & 127;
    int trg = (t == 0) ? 512 : x[b * 128 + t - 1];
    float yv = y[b];
    const float* e = emb + (size_t)trg * 512 + h0;
    bf16x8 v;
    #pragma unroll
    for (int i = 0; i < 8; ++i) v[i] = (bf16)(e[i] + yv * yW[h0 + i] + yb[h0 + i]);
    *(bf16x8*)&inp[(size_t)bt * 512 + h0] = v;
}

// ---------------------------------------------------------------------------
// C[M,N] = A[M,512] * W[N,512]^T + bias[N]   (proven 128x128 MFMA tile)
// ---------------------------------------------------------------------------
template <bool OUT_BF16>
__global__ __launch_bounds__(256) void gemm_bt(const bf16* __restrict__ A,
                                               const bf16* __restrict__ W,
                                               const float* __restrict__ bias,
                                               void* __restrict__ Cout, int M, int N) {
    constexpr int K = 512;
    __shared__ bf16 As[128][40];
    __shared__ bf16 Ws[128][40];
    int bid = blockIdx.x;
    int nTiles = N / 128;
    int m0 = (bid / nTiles) * 128;
    int n0 = (bid % nTiles) * 128;
    int tid = threadIdx.x;
    int wave = tid >> 6, lane = tid & 63;
    int quad = lane >> 4, l16 = lane & 15;
    int wm = (wave & 1) * 64, wn = (wave >> 1) * 64;
    f32x4 acc[4][4] = {};

    for (int k0 = 0; k0 < K; k0 += 32) {
        __syncthreads();
        #pragma unroll
        for (int r = 0; r < 2; ++r) {
            int c = tid + 256 * r;
            int row = c >> 2, col = (c & 3) * 8;
            *(bf16x8*)&As[row][col] = *(const bf16x8*)&A[(size_t)(m0 + row) * K + k0 + col];
            *(bf16x8*)&Ws[row][col] = *(const bf16x8*)&W[(size_t)(n0 + row) * K + k0 + col];
        }
        __syncthreads();
        bf16x8 af[4], bfr[4];
        #pragma unroll
        for (int i = 0; i < 4; ++i) af[i] = *(const bf16x8*)&As[wm + i * 16 + l16][quad * 8];
        #pragma unroll
        for (int i = 0; i < 4; ++i) bfr[i] = *(const bf16x8*)&Ws[wn + i * 16 + l16][quad * 8];
        #pragma unroll
        for (int mt = 0; mt < 4; ++mt)
            #pragma unroll
            for (int nt = 0; nt < 4; ++nt)
                acc[mt][nt] = __builtin_amdgcn_mfma_f32_16x16x32_bf16(af[mt], bfr[nt], acc[mt][nt], 0, 0, 0);
    }

    #pragma unroll
    for (int mt = 0; mt < 4; ++mt)
        #pragma unroll
        for (int nt = 0; nt < 4; ++nt) {
            int row = m0 + wm + mt * 16 + quad * 4;
            int col = n0 + wn + nt * 16 + l16;
            float bv = bias[col];
            #pragma unroll
            for (int i = 0; i < 4; ++i) {
                float v = acc[mt][nt][i] + bv;
                if (OUT_BF16) ((bf16*)Cout)[(size_t)(row + i) * N + col] = (bf16)v;
                else          ((float*)Cout)[(size_t)(row + i) * N + col] = v;
            }
        }
}

// ---------------------------------------------------------------------------
// Persistent LSTM scan: one launch per layer, 128 timesteps inside.
// Grid 256 = 16 batch-tiles x 16 hh-tiles. Wave w = gate w; its 32x512 Whh
// slice is register-resident (128 VGPRs). c-state register-resident (4/thr).
// h ping-pongs in global; one device-scope atomic barrier per step.
// ---------------------------------------------------------------------------
#define NBLK 256
#define HS_STRIDE 520   // bf16 stride: 2-way bank pattern on frag reads (free)

__device__ __forceinline__ void gridbar(unsigned* cnt, unsigned target) {
    __syncthreads();                       // drains each wave's vmcnt before barrier
    if (threadIdx.x == 0) {
        __threadfence();                   // release: write-back this XCD's L2
        atomicAdd(cnt, 1u);                // device-scope
        while (__hip_atomic_load(cnt, __ATOMIC_ACQUIRE, __HIP_MEMORY_SCOPE_AGENT) < target)
            __builtin_amdgcn_s_sleep(1);
        __threadfence();                   // acquire: invalidate L1/L2
    }
    __syncthreads();
}

__global__ __launch_bounds__(256) void lstm_scan(const bf16* __restrict__ xg,
                                                 const bf16* __restrict__ Wh,
                                                 bf16* __restrict__ hA,
                                                 bf16* __restrict__ hB,
                                                 bf16* __restrict__ h_all,
                                                 unsigned* __restrict__ barcnt) {
    constexpr int T = 128;
    __shared__ bf16 Hs[32][HS_STRIDE];
    __shared__ float gs[4][32][33];
    int tid = threadIdx.x;
    int b0 = (blockIdx.x >> 4) * 32;
    int n0 = (blockIdx.x & 15) * 32;
    int wave = tid >> 6, lane = tid & 63;
    int quad = lane >> 4, l16 = lane & 15;

    // Whh gate slice -> registers (loaded once for all 128 steps)
    bf16x8 wreg[2][16];
    const bf16* wbase = Wh + (size_t)(wave * 512 + n0) * 512;
    #pragma unroll
    for (int nt = 0; nt < 2; ++nt)
        #pragma unroll
        for (int kc = 0; kc < 16; ++kc)
            wreg[nt][kc] = *(const bf16x8*)&wbase[(size_t)(nt * 16 + l16) * 512 + kc * 32 + quad * 8];

    // epilogue mapping (fixed for the whole scan)
    int m = tid >> 3;                 // 0..31 (batch row in tile)
    int nl0 = (tid & 7) * 4;          // 0,4,...,28 (hh col in tile)
    int b = b0 + m;
    float cc[4] = {0.f, 0.f, 0.f, 0.f};   // register-resident c-state

    // zero own tile of hA (h_prev for t=0)
    {
        bf16x4 z = {};
        *(bf16x4*)&hA[(size_t)b * 512 + n0 + nl0] = z;
    }

    bf16* hp = hA;
    bf16* hn = hB;
    unsigned gen = 0;

    for (int t = 0; t < T; ++t) {
        gen += NBLK;
        gridbar(barcnt, gen);         // h_prev (or zero-init) globally visible

        // stage h_prev rows b0..b0+31 (all 512 cols) -> LDS, coalesced
        #pragma unroll
        for (int r = 0; r < 8; ++r) {
            int c = r * 256 + tid;            // 2048 chunks of 8 bf16
            int row = c >> 6, col = (c & 63) * 8;
            *(bf16x8*)&Hs[row][col] = *(const bf16x8*)&hp[(size_t)(b0 + row) * 512 + col];
        }
        __syncthreads();

        // MFMA: acc[mt][nt] over K=512
        f32x4 acc[2][2] = {};
        #pragma unroll
        for (int kc = 0; kc < 16; ++kc) {
            bf16x8 af0 = *(const bf16x8*)&Hs[l16][kc * 32 + quad * 8];
            bf16x8 af1 = *(const bf16x8*)&Hs[16 + l16][kc * 32 + quad * 8];
            acc[0][0] = __builtin_amdgcn_mfma_f32_16x16x32_bf16(af0, wreg[0][kc], acc[0][0], 0, 0, 0);
            acc[0][1] = __builtin_amdgcn_mfma_f32_16x16x32_bf16(af0, wreg[1][kc], acc[0][1], 0, 0, 0);
            acc[1][0] = __builtin_amdgcn_mfma_f32_16x16x32_bf16(af1, wreg[0][kc], acc[1][0], 0, 0, 0);
            acc[1][1] = __builtin_amdgcn_mfma_f32_16x16x32_bf16(af1, wreg[1][kc], acc[1][1], 0, 0, 0);
        }
        __syncthreads();              // Hs reads done; gs from prev step consumed (barrier)

        #pragma unroll
        for (int mt = 0; mt < 2; ++mt)
            #pragma unroll
            for (int nt = 0; nt < 2; ++nt)
                #pragma unroll
                for (int i = 0; i < 4; ++i)
                    gs[wave][mt * 16 + quad * 4 + i][nt * 16 + l16] = acc[mt][nt][i];
        __syncthreads();

        // gates + state update (c in registers)
        size_t xrow = ((size_t)b * T + t) * 2048;
        bf16x4 xi = *(const bf16x4*)&xg[xrow + 0 * 512 + n0 + nl0];
        bf16x4 xf = *(const bf16x4*)&xg[xrow + 1 * 512 + n0 + nl0];
        bf16x4 xgg = *(const bf16x4*)&xg[xrow + 2 * 512 + n0 + nl0];
        bf16x4 xo = *(const bf16x4*)&xg[xrow + 3 * 512 + n0 + nl0];
        bf16x4 hv;
        #pragma unroll
        for (int ii = 0; ii < 4; ++ii) {
            int n = nl0 + ii;
            float gi = gs[0][m][n] + (float)xi[ii];
            float gf = gs[1][m][n] + (float)xf[ii];
            float gg = gs[2][m][n] + (float)xgg[ii];
            float go = gs[3][m][n] + (float)xo[ii];
            float iv = 1.f / (1.f + __expf(-gi));
            float fv = 1.f / (1.f + __expf(-gf));
            float gv = tanhf(gg);
            float ov = 1.f / (1.f + __expf(-go));
            float cn = fv * cc[ii] + iv * gv;
            float hnv = ov * tanhf(cn);
            cc[ii] = cn;
            hv[ii] = (bf16)hnv;
        }
        *(bf16x4*)&hn[(size_t)b * 512 + n0 + nl0] = hv;
        *(bf16x4*)&h_all[((size_t)b * T + t) * 512 + n0 + nl0] = hv;

        bf16* tmp = hp; hp = hn; hn = tmp;
    }
}

// ---------------------------------------------------------------------------
extern "C" void kernel_launch(void* const* d_in, const int* in_sizes, int n_in,
                              void* d_out, int out_size, void* d_ws, size_t ws_size,
                              hipStream_t stream) {
    const int*   x    = (const int*)d_in[0];
    const float* y    = (const float*)d_in[1];
    const float* emb  = (const float*)d_in[2];
    const float* yW   = (const float*)d_in[3];
    const float* yb   = (const float*)d_in[4];
    const float* Wih  = (const float*)d_in[5];
    const float* Whh  = (const float*)d_in[6];
    const float* bih  = (const float*)d_in[7];
    const float* bhh  = (const float*)d_in[8];
    const float* decW = (const float*)d_in[9];
    const float* decb = (const float*)d_in[10];
    float* out = (float*)d_out;

    char* ws = (char*)d_ws;
    size_t off = 0;
    auto alloc = [&](size_t bytes) {
        char* p = ws + off;
        off += (bytes + 255) & ~(size_t)255;
        return p;
    };
    bf16*  inp   = (bf16*)alloc(65536ull * 512 * 2);    //  64 MB
    bf16*  xg    = (bf16*)alloc(65536ull * 2048 * 2);   // 256 MB
    bf16*  WihB  = (bf16*)alloc(2097152ull * 2);
    bf16*  WhhB  = (bf16*)alloc(2097152ull * 2);
    bf16*  decWB = (bf16*)alloc(262144ull * 2);
    float* bias  = (float*)alloc(4096ull * 4);
    bf16*  hA    = (bf16*)alloc(512ull * 512 * 2);
    bf16*  hB    = (bf16*)alloc(512ull * 512 * 2);
    unsigned* cnt = (unsigned*)alloc(512);

    hipMemsetAsync(cnt, 0, 512, stream);   // barrier counters (one per layer)
    convert_w<<<17424, 256, 0, stream>>>(Wih, Whh, decW, bih, bhh, WihB, WhhB, decWB, bias);
    prep_inp<<<16384, 256, 0, stream>>>(x, y, emb, yW, yb, inp);

    const size_t LSTRIDE = 2048ull * 512;   // per-layer weight elements
    for (int l = 0; l < 2; ++l) {
        gemm_bt<true><<<512 * 16, 256, 0, stream>>>(inp, WihB + (size_t)l * LSTRIDE,
                                                    bias + l * 2048, xg, 65536, 2048);
        lstm_scan<<<NBLK, 256, 0, stream>>>(xg, WhhB + (size_t)l * LSTRIDE,
                                            hA, hB, inp, cnt + (size_t)l * 64);
    }
    gemm_bt<false><<<512 * 4, 256, 0, stream>>>(inp, decWB, decb, out, 65536, 512);
}

// Round 4
// 2235.581 us; speedup vs baseline: 3.5951x; 3.5951x over previous
//
#include <hip/hip_runtime.h>
#include <hip/hip_bf16.h>
#include <string.h>

typedef __bf16 bf16;
typedef __bf16 bf16x8 __attribute__((ext_vector_type(8)));
typedef __bf16 bf16x4 __attribute__((ext_vector_type(4)));
typedef float f32x4 __attribute__((ext_vector_type(4)));
typedef unsigned long long ull;

// ---------------------------------------------------------------------------
// Weight conversion fp32 -> bf16, and combined bias bih+bhh
// ---------------------------------------------------------------------------
__global__ void convert_w(const float* __restrict__ Wih, const float* __restrict__ Whh,
                          const float* __restrict__ decW, const float* __restrict__ bih,
                          const float* __restrict__ bhh,
                          bf16* __restrict__ WihB, bf16* __restrict__ WhhB,
                          bf16* __restrict__ decWB, float* __restrict__ bias) {
    int idx = blockIdx.x * 256 + threadIdx.x;
    const int NW = 2 * 2048 * 512;           // 2097152 (both layers)
    if (idx < NW) {
        WihB[idx] = (bf16)Wih[idx];
    } else if (idx < 2 * NW) {
        WhhB[idx - NW] = (bf16)Whh[idx - NW];
    } else if (idx < 2 * NW + 512 * 512) {
        decWB[idx - 2 * NW] = (bf16)decW[idx - 2 * NW];
    } else if (idx < 2 * NW + 512 * 512 + 4096) {
        int j = idx - (2 * NW + 512 * 512);
        bias[j] = bih[j] + bhh[j];
    }
}

// ---------------------------------------------------------------------------
// inp[b,t,h] = emb[trg[b,t], h] + y[b]*yW[h] + yb[h]   (bf16 out)
// ---------------------------------------------------------------------------
__global__ void prep_inp(const int* __restrict__ x, const float* __restrict__ y,
                         const float* __restrict__ emb, const float* __restrict__ yW,
                         const float* __restrict__ yb, bf16* __restrict__ inp) {
    int idx = blockIdx.x * 256 + threadIdx.x;   // total 65536*64
    int bt = idx >> 6;
    int h0 = (idx & 63) * 8;
    int b = bt >> 7, t = bt & 127;
    int trg = (t == 0) ? 512 : x[b * 128 + t - 1];
    float yv = y[b];
    const float* e = emb + (size_t)trg * 512 + h0;
    bf16x8 v;
    #pragma unroll
    for (int i = 0; i < 8; ++i) v[i] = (bf16)(e[i] + yv * yW[h0 + i] + yb[h0 + i]);
    *(bf16x8*)&inp[(size_t)bt * 512 + h0] = v;
}

// ---------------------------------------------------------------------------
// C[M,N] = A[M,512] * W[N,512]^T + bias[N]   (proven 128x128 MFMA tile)
// ---------------------------------------------------------------------------
template <bool OUT_BF16>
__global__ __launch_bounds__(256) void gemm_bt(const bf16* __restrict__ A,
                                               const bf16* __restrict__ W,
                                               const float* __restrict__ bias,
                                               void* __restrict__ Cout, int M, int N) {
    constexpr int K = 512;
    __shared__ bf16 As[128][40];
    __shared__ bf16 Ws[128][40];
    int bid = blockIdx.x;
    int nTiles = N / 128;
    int m0 = (bid / nTiles) * 128;
    int n0 = (bid % nTiles) * 128;
    int tid = threadIdx.x;
    int wave = tid >> 6, lane = tid & 63;
    int quad = lane >> 4, l16 = lane & 15;
    int wm = (wave & 1) * 64, wn = (wave >> 1) * 64;
    f32x4 acc[4][4] = {};

    for (int k0 = 0; k0 < K; k0 += 32) {
        __syncthreads();
        #pragma unroll
        for (int r = 0; r < 2; ++r) {
            int c = tid + 256 * r;
            int row = c >> 2, col = (c & 3) * 8;
            *(bf16x8*)&As[row][col] = *(const bf16x8*)&A[(size_t)(m0 + row) * K + k0 + col];
            *(bf16x8*)&Ws[row][col] = *(const bf16x8*)&W[(size_t)(n0 + row) * K + k0 + col];
        }
        __syncthreads();
        bf16x8 af[4], bfr[4];
        #pragma unroll
        for (int i = 0; i < 4; ++i) af[i] = *(const bf16x8*)&As[wm + i * 16 + l16][quad * 8];
        #pragma unroll
        for (int i = 0; i < 4; ++i) bfr[i] = *(const bf16x8*)&Ws[wn + i * 16 + l16][quad * 8];
        #pragma unroll
        for (int mt = 0; mt < 4; ++mt)
            #pragma unroll
            for (int nt = 0; nt < 4; ++nt)
                acc[mt][nt] = __builtin_amdgcn_mfma_f32_16x16x32_bf16(af[mt], bfr[nt], acc[mt][nt], 0, 0, 0);
    }

    #pragma unroll
    for (int mt = 0; mt < 4; ++mt)
        #pragma unroll
        for (int nt = 0; nt < 4; ++nt) {
            int row = m0 + wm + mt * 16 + quad * 4;
            int col = n0 + wn + nt * 16 + l16;
            float bv = bias[col];
            #pragma unroll
            for (int i = 0; i < 4; ++i) {
                float v = acc[mt][nt][i] + bv;
                if (OUT_BF16) ((bf16*)Cout)[(size_t)(row + i) * N + col] = (bf16)v;
                else          ((float*)Cout)[(size_t)(row + i) * N + col] = v;
            }
        }
}

// ---------------------------------------------------------------------------
// Persistent LSTM scan, fence-free producer/consumer.
// Grid 128 = 16 batch-tile groups x 8 hh-tile blocks; block = 512 thr (8 waves).
// Wave (g,s) = gate g, 32-col half s; its 32x512 Whh slice register-resident.
// Sync: per-group (8 blocks) counter; h exchanged via relaxed agent-scope
// atomic b64 ops (coherent, NO cache-maintenance fences).
// Order: h stores -> s_waitcnt vmcnt(0) (per wave) -> syncthreads -> +1.
// ---------------------------------------------------------------------------
#define GROUP 8
#define HS_STRIDE 520

__global__ __launch_bounds__(512, 2) void lstm_scan(const bf16* __restrict__ xg,
                                                    const bf16* __restrict__ Wh,
                                                    bf16* __restrict__ hA,
                                                    bf16* __restrict__ hB,
                                                    bf16* __restrict__ h_all,
                                                    unsigned* __restrict__ barcnt) {
    constexpr int T = 128;
    __shared__ bf16 Hs[32][HS_STRIDE];
    __shared__ float gs[8][32][33];
    int tid = threadIdx.x;
    int bt = blockIdx.x >> 3;          // batch tile 0..15
    int q  = blockIdx.x & 7;           // hh tile (64 cols) 0..7
    int b0 = bt * 32;
    int n0 = q * 64;
    int w = tid >> 6, lane = tid & 63;
    int quad = lane >> 4, l16 = lane & 15;
    int g = w >> 1, s = w & 1;         // gate, 32-col half
    unsigned* cnt = barcnt + bt * 64;  // one line per group

    // Whh slice -> registers (once for all 128 steps): rows g*512+n0+32s .. +31
    bf16x8 wreg[2][16];
    const bf16* wbase = Wh + ((size_t)g * 512 + n0 + 32 * s) * 512;
    #pragma unroll
    for (int nt = 0; nt < 2; ++nt)
        #pragma unroll
        for (int kc = 0; kc < 16; ++kc)
            wreg[nt][kc] = *(const bf16x8*)&wbase[(size_t)(nt * 16 + l16) * 512 + kc * 32 + quad * 8];

    // epilogue mapping: 512 threads <-> 32 batch x 64 cols, 4 cols each
    int m = tid >> 4;                  // 0..31
    int nl0 = (tid & 15) * 4;          // 0..60
    int b = b0 + m;
    int half = nl0 >> 5;               // which 32-col half
    int nn = nl0 & 31;                 // col within half
    float cc[4] = {0.f, 0.f, 0.f, 0.f};

    // zero own hA slice (coherent stores), then arrive
    __hip_atomic_store((ull*)&hA[(size_t)b * 512 + n0 + nl0], 0ull,
                       __ATOMIC_RELAXED, __HIP_MEMORY_SCOPE_AGENT);
    asm volatile("s_waitcnt vmcnt(0)" ::: "memory");
    __syncthreads();
    if (tid == 0) __hip_atomic_fetch_add(cnt, 1u, __ATOMIC_RELAXED, __HIP_MEMORY_SCOPE_AGENT);

    const bf16* hp = hA;
    bf16* hn = hB;

    for (int t = 0; t < T; ++t) {
        // prefetch this step's xg into registers (overlaps the poll)
        size_t xrow = ((size_t)b * T + t) * 2048 + n0 + nl0;
        bf16x4 xv[4];
        #pragma unroll
        for (int gg = 0; gg < 4; ++gg) xv[gg] = *(const bf16x4*)&xg[xrow + (size_t)gg * 512];

        // group barrier: wait until all 8 peers stored h for step t-1
        if (tid == 0) {
            unsigned target = GROUP * (unsigned)(t + 1);
            while (__hip_atomic_load(cnt, __ATOMIC_RELAXED, __HIP_MEMORY_SCOPE_AGENT) < target)
                __builtin_amdgcn_s_sleep(2);
        }
        __syncthreads();

        // coherent read h_prev rows b0..b0+31 (512 cols) -> LDS
        #pragma unroll
        for (int i = 0; i < 8; ++i) {
            int idx = i * 512 + tid;           // 4096 b64 chunks
            int row = idx >> 7, colb = idx & 127;
            ull v = __hip_atomic_load((const ull*)&hp[(size_t)(b0 + row) * 512 + colb * 4],
                                      __ATOMIC_RELAXED, __HIP_MEMORY_SCOPE_AGENT);
            *(ull*)&Hs[row][colb * 4] = v;
        }
        __syncthreads();

        // MFMA over K=512: out 32 batch x 32 cols per wave
        f32x4 acc[2][2] = {};
        #pragma unroll
        for (int kc = 0; kc < 16; ++kc) {
            bf16x8 af0 = *(const bf16x8*)&Hs[l16][kc * 32 + quad * 8];
            bf16x8 af1 = *(const bf16x8*)&Hs[16 + l16][kc * 32 + quad * 8];
            acc[0][0] = __builtin_amdgcn_mfma_f32_16x16x32_bf16(af0, wreg[0][kc], acc[0][0], 0, 0, 0);
            acc[0][1] = __builtin_amdgcn_mfma_f32_16x16x32_bf16(af0, wreg[1][kc], acc[0][1], 0, 0, 0);
            acc[1][0] = __builtin_amdgcn_mfma_f32_16x16x32_bf16(af1, wreg[0][kc], acc[1][0], 0, 0, 0);
            acc[1][1] = __builtin_amdgcn_mfma_f32_16x16x32_bf16(af1, wreg[1][kc], acc[1][1], 0, 0, 0);
        }
        #pragma unroll
        for (int mt = 0; mt < 2; ++mt)
            #pragma unroll
            for (int nt = 0; nt < 2; ++nt)
                #pragma unroll
                for (int i = 0; i < 4; ++i)
                    gs[w][mt * 16 + quad * 4 + i][nt * 16 + l16] = acc[mt][nt][i];
        __syncthreads();

        // gates + state update (c register-resident)
        bf16x4 hv;
        #pragma unroll
        for (int ii = 0; ii < 4; ++ii) {
            float gi = gs[0 * 2 + half][m][nn + ii] + (float)xv[0][ii];
            float gf = gs[1 * 2 + half][m][nn + ii] + (float)xv[1][ii];
            float gg = gs[2 * 2 + half][m][nn + ii] + (float)xv[2][ii];
            float go = gs[3 * 2 + half][m][nn + ii] + (float)xv[3][ii];
            float iv = 1.f / (1.f + __expf(-gi));
            float fv = 1.f / (1.f + __expf(-gf));
            float gv = tanhf(gg);
            float ov = 1.f / (1.f + __expf(-go));
            float cn = fv * cc[ii] + iv * gv;
            float hnv = ov * tanhf(cn);
            cc[ii] = cn;
            hv[ii] = (bf16)hnv;
        }
        ull hbits;
        memcpy(&hbits, &hv, 8);
        __hip_atomic_store((ull*)&hn[(size_t)b * 512 + n0 + nl0], hbits,
                           __ATOMIC_RELAXED, __HIP_MEMORY_SCOPE_AGENT);
        *(bf16x4*)&h_all[((size_t)b * T + t) * 512 + n0 + nl0] = hv;    // plain: next dispatch
        asm volatile("s_waitcnt vmcnt(0)" ::: "memory");
        __syncthreads();
        if (tid == 0) __hip_atomic_fetch_add(cnt, 1u, __ATOMIC_RELAXED, __HIP_MEMORY_SCOPE_AGENT);

        const bf16* tmp = hp; hp = hn; hn = (bf16*)tmp;
    }
}

// ---------------------------------------------------------------------------
extern "C" void kernel_launch(void* const* d_in, const int* in_sizes, int n_in,
                              void* d_out, int out_size, void* d_ws, size_t ws_size,
                              hipStream_t stream) {
    const int*   x    = (const int*)d_in[0];
    const float* y    = (const float*)d_in[1];
    const float* emb  = (const float*)d_in[2];
    const float* yW   = (const float*)d_in[3];
    const float* yb   = (const float*)d_in[4];
    const float* Wih  = (const float*)d_in[5];
    const float* Whh  = (const float*)d_in[6];
    const float* bih  = (const float*)d_in[7];
    const float* bhh  = (const float*)d_in[8];
    const float* decW = (const float*)d_in[9];
    const float* decb = (const float*)d_in[10];
    float* out = (float*)d_out;

    char* ws = (char*)d_ws;
    size_t off = 0;
    auto alloc = [&](size_t bytes) {
        char* p = ws + off;
        off += (bytes + 255) & ~(size_t)255;
        return p;
    };
    bf16*  inp   = (bf16*)alloc(65536ull * 512 * 2);    //  64 MB
    bf16*  xg    = (bf16*)alloc(65536ull * 2048 * 2);   // 256 MB
    bf16*  WihB  = (bf16*)alloc(2097152ull * 2);
    bf16*  WhhB  = (bf16*)alloc(2097152ull * 2);
    bf16*  decWB = (bf16*)alloc(262144ull * 2);
    float* bias  = (float*)alloc(4096ull * 4);
    bf16*  hA    = (bf16*)alloc(512ull * 512 * 2);
    bf16*  hB    = (bf16*)alloc(512ull * 512 * 2);
    unsigned* cnt = (unsigned*)alloc(2 * 16 * 64 * 4);  // 2 layers x 16 groups

    hipMemsetAsync(cnt, 0, 2 * 16 * 64 * 4, stream);
    convert_w<<<17424, 256, 0, stream>>>(Wih, Whh, decW, bih, bhh, WihB, WhhB, decWB, bias);
    prep_inp<<<16384, 256, 0, stream>>>(x, y, emb, yW, yb, inp);

    const size_t LSTRIDE = 2048ull * 512;   // per-layer weight elements
    for (int l = 0; l < 2; ++l) {
        gemm_bt<true><<<512 * 16, 256, 0, stream>>>(inp, WihB + (size_t)l * LSTRIDE,
                                                    bias + l * 2048, xg, 65536, 2048);
        lstm_scan<<<128, 512, 0, stream>>>(xg, WhhB + (size_t)l * LSTRIDE,
                                           hA, hB, inp, cnt + (size_t)l * 16 * 64);
    }
    gemm_bt<false><<<512 * 4, 256, 0, stream>>>(inp, decWB, decb, out, 65536, 512);
}